// Round 1
// baseline (55.744 us; speedup 1.0000x reference)
//
#include <hip/hip_runtime.h>

#define HOMO_BOOST_THRD 0.5f
#define HOMO_LOSS_WEIGHT 100.0f
#define COS_EPS 1e-8f
#define D_FEAT 128

// Scatter membership flags: first n_tgt threads set tgt_flag, next n_bkd set bkd_flag.
__global__ void scatter_flags_kernel(const int* __restrict__ target_nodes, int n_tgt,
                                     const int* __restrict__ bkd_nodes, int n_bkd,
                                     unsigned char* __restrict__ tgt_flag,
                                     unsigned char* __restrict__ bkd_flag) {
    int i = blockIdx.x * blockDim.x + threadIdx.x;
    if (i < n_tgt) {
        tgt_flag[target_nodes[i]] = 1;
    } else {
        int j = i - n_tgt;
        if (j < n_bkd) bkd_flag[bkd_nodes[j]] = 1;
    }
}

__global__ void edge_loss_kernel(const int* __restrict__ edge_index,   // [2*E], row0=u, row1=v
                                 const float* __restrict__ edge_weights,
                                 const float* __restrict__ x,          // [N, 128]
                                 const unsigned char* __restrict__ tgt_flag,
                                 const unsigned char* __restrict__ bkd_flag,
                                 float* __restrict__ out, int E) {
    int stride = gridDim.x * blockDim.x;
    float acc = 0.0f;
    for (int e = blockIdx.x * blockDim.x + threadIdx.x; e < E; e += stride) {
        int u = edge_index[e];
        int v = edge_index[E + e];
        // membership mask (cheap, L1/L2-resident 50KB bitmaps)
        bool m = (bkd_flag[u] && tgt_flag[v]) || (bkd_flag[v] && tgt_flag[u]);
        if (!m) continue;
        // only touch the weight stream for masked edges (rare)
        if (edge_weights[e] == 0.0f) continue;

        const float4* xu = reinterpret_cast<const float4*>(x + (size_t)u * D_FEAT);
        const float4* xv = reinterpret_cast<const float4*>(x + (size_t)v * D_FEAT);
        float dot = 0.0f, nu2 = 0.0f, nv2 = 0.0f;
        #pragma unroll
        for (int k = 0; k < D_FEAT / 4; ++k) {
            float4 a = xu[k];
            float4 b = xv[k];
            dot += a.x * b.x + a.y * b.y + a.z * b.z + a.w * b.w;
            nu2 += a.x * a.x + a.y * a.y + a.z * a.z + a.w * a.w;
            nv2 += b.x * b.x + b.y * b.y + b.z * b.z + b.w * b.w;
        }
        float nu = fmaxf(sqrtf(nu2), COS_EPS);
        float nv = fmaxf(sqrtf(nv2), COS_EPS);
        float sim = dot / (nu * nv);
        acc += fmaxf(HOMO_BOOST_THRD - sim, 0.0f);
    }
    if (acc != 0.0f) {
        atomicAdd(out, acc * HOMO_LOSS_WEIGHT);
    }
}

extern "C" void kernel_launch(void* const* d_in, const int* in_sizes, int n_in,
                              void* d_out, int out_size, void* d_ws, size_t ws_size,
                              hipStream_t stream) {
    const int*   edge_index   = (const int*)  d_in[0];   // [2*E] int32
    const float* edge_weights = (const float*)d_in[1];   // [E]
    const float* x            = (const float*)d_in[2];   // [N,128]
    const int*   target_nodes = (const int*)  d_in[3];   // [n_tgt]
    const int*   bkd_nodes    = (const int*)  d_in[4];   // [n_bkd]

    const int E     = in_sizes[0] / 2;
    const int N     = in_sizes[2] / D_FEAT;
    const int n_tgt = in_sizes[3];
    const int n_bkd = in_sizes[4];

    unsigned char* tgt_flag = (unsigned char*)d_ws;
    unsigned char* bkd_flag = tgt_flag + N;

    // zero output scalar and the two N-byte flag arrays (deterministic per call)
    hipMemsetAsync(d_out, 0, sizeof(float), stream);
    hipMemsetAsync(d_ws, 0, (size_t)(2 * N), stream);

    int scatter_threads = n_tgt + n_bkd;
    scatter_flags_kernel<<<(scatter_threads + 255) / 256, 256, 0, stream>>>(
        target_nodes, n_tgt, bkd_nodes, n_bkd, tgt_flag, bkd_flag);

    int blocks = (E + 255) / 256;
    if (blocks > 2048) blocks = 2048;  // grid-stride, ~8 blocks/CU
    edge_loss_kernel<<<blocks, 256, 0, stream>>>(
        edge_index, edge_weights, x, tgt_flag, bkd_flag, (float*)d_out, E);
}

// Round 2
// 34.022 us; speedup vs baseline: 1.6385x; 1.6385x over previous
//
#include <hip/hip_runtime.h>

#define HOMO_BOOST_THRD 0.5f
#define HOMO_LOSS_WEIGHT 100.0f
#define COS_EPS 1e-8f
#define D_FEAT 128

// Combined membership flags: bit0 = bkd, bit1 = tgt. atomicOr on the containing
// word (a node can appear in both sets; byte RMW would race).
__global__ void scatter_flags_kernel(const int* __restrict__ target_nodes, int n_tgt,
                                     const int* __restrict__ bkd_nodes, int n_bkd,
                                     unsigned int* __restrict__ flags_w) {
    int i = blockIdx.x * blockDim.x + threadIdx.x;
    int node, bit;
    if (i < n_tgt) {
        node = target_nodes[i];
        bit = 2;
    } else {
        int j = i - n_tgt;
        if (j >= n_bkd) return;
        node = bkd_nodes[j];
        bit = 1;
    }
    atomicOr(&flags_w[node >> 2], (unsigned int)bit << ((node & 3) * 8));
}

__global__ void edge_loss_kernel(const int* __restrict__ edge_index,   // [2*E]
                                 const float* __restrict__ edge_weights,
                                 const float* __restrict__ x,          // [N,128]
                                 const unsigned char* __restrict__ flags,
                                 float* __restrict__ partials, int E) {
    __shared__ float wsum[4];
    int e = blockIdx.x * blockDim.x + threadIdx.x;
    float val = 0.0f;
    if (e < E) {
        int u = edge_index[e];
        int v = edge_index[E + e];
        unsigned int fu = flags[u];
        unsigned int fv = flags[v];
        // bit0=bkd, bit1=tgt
        bool m = ((fu & 1u) && (fv & 2u)) || ((fv & 1u) && (fu & 2u));
        if (m && edge_weights[e] != 0.0f) {
            const float4* xu = reinterpret_cast<const float4*>(x + (size_t)u * D_FEAT);
            const float4* xv = reinterpret_cast<const float4*>(x + (size_t)v * D_FEAT);
            float dot = 0.0f, nu2 = 0.0f, nv2 = 0.0f;
            #pragma unroll
            for (int k = 0; k < D_FEAT / 4; ++k) {
                float4 a = xu[k];
                float4 b = xv[k];
                dot += a.x * b.x + a.y * b.y + a.z * b.z + a.w * b.w;
                nu2 += a.x * a.x + a.y * a.y + a.z * a.z + a.w * a.w;
                nv2 += b.x * b.x + b.y * b.y + b.z * b.z + b.w * b.w;
            }
            float nu = fmaxf(sqrtf(nu2), COS_EPS);
            float nv = fmaxf(sqrtf(nv2), COS_EPS);
            val = fmaxf(HOMO_BOOST_THRD - dot / (nu * nv), 0.0f);
        }
    }
    // wave reduce (64 lanes)
    #pragma unroll
    for (int off = 32; off > 0; off >>= 1) val += __shfl_down(val, off, 64);
    int wid = threadIdx.x >> 6;
    if ((threadIdx.x & 63) == 0) wsum[wid] = val;
    __syncthreads();
    if (threadIdx.x == 0)
        partials[blockIdx.x] = wsum[0] + wsum[1] + wsum[2] + wsum[3];
}

__global__ void reduce_kernel(const float* __restrict__ partials, int n,
                              float* __restrict__ out) {
    __shared__ float wsum[4];
    float s = 0.0f;
    for (int i = threadIdx.x; i < n; i += blockDim.x) s += partials[i];
    #pragma unroll
    for (int off = 32; off > 0; off >>= 1) s += __shfl_down(s, off, 64);
    int wid = threadIdx.x >> 6;
    if ((threadIdx.x & 63) == 0) wsum[wid] = s;
    __syncthreads();
    if (threadIdx.x == 0)
        out[0] = (wsum[0] + wsum[1] + wsum[2] + wsum[3]) * HOMO_LOSS_WEIGHT;
}

extern "C" void kernel_launch(void* const* d_in, const int* in_sizes, int n_in,
                              void* d_out, int out_size, void* d_ws, size_t ws_size,
                              hipStream_t stream) {
    const int*   edge_index   = (const int*)  d_in[0];
    const float* edge_weights = (const float*)d_in[1];
    const float* x            = (const float*)d_in[2];
    const int*   target_nodes = (const int*)  d_in[3];
    const int*   bkd_nodes    = (const int*)  d_in[4];

    const int E     = in_sizes[0] / 2;
    const int N     = in_sizes[2] / D_FEAT;
    const int n_tgt = in_sizes[3];
    const int n_bkd = in_sizes[4];

    // ws layout: [flags: N bytes (word-aligned)] [partials: nblocks floats]
    size_t flags_bytes = ((size_t)N + 3) & ~(size_t)3;
    unsigned char* flags = (unsigned char*)d_ws;
    const int nblocks = (E + 255) / 256;
    float* partials = (float*)((char*)d_ws + flags_bytes);

    hipMemsetAsync(d_ws, 0, flags_bytes, stream);

    int scatter_threads = n_tgt + n_bkd;
    scatter_flags_kernel<<<(scatter_threads + 255) / 256, 256, 0, stream>>>(
        target_nodes, n_tgt, bkd_nodes, n_bkd, (unsigned int*)flags);

    edge_loss_kernel<<<nblocks, 256, 0, stream>>>(
        edge_index, edge_weights, x, flags, partials, E);

    reduce_kernel<<<1, 256, 0, stream>>>(partials, nblocks, (float*)d_out);
}